// Round 3
// baseline (441.234 us; speedup 1.0000x reference)
//
#include <hip/hip_runtime.h>
#include <cstdint>

#define N_NODES 4096
#define DM 64
#define K_DIM 8192   // S*N
#define M_DIM 2048   // B*DM

typedef uint8_t u8;
using i32x8   = __attribute__((ext_vector_type(8))) int;
using floatx4 = __attribute__((ext_vector_type(4))) float;

#define GLOAD_LDS16(gp, lp)                                                     \
  __builtin_amdgcn_global_load_lds(                                             \
      reinterpret_cast<const __attribute__((address_space(1))) void*>(          \
          reinterpret_cast<uintptr_t>(gp)),                                     \
      reinterpret_cast<__attribute__((address_space(3))) void*>(                \
          (uint32_t)reinterpret_cast<uintptr_t>(lp)),                           \
      16, 0, 0)

// pack 4 floats -> 4 fp8(e4m3) bytes in one int, byte i = f[i]
__device__ inline int pk_fp8x4(float f0, float f1, float f2, float f3) {
  int r = __builtin_amdgcn_cvt_pk_fp8_f32(f0, f1, 0, false);   // bytes 0,1
  r     = __builtin_amdgcn_cvt_pk_fp8_f32(f2, f3, r, true);    // bytes 2,3
  return r;
}

// ---------------- kernel 1 (fused prep) — UNCHANGED from verified v2:
// blocks [0,1024):    A8 build (folded W_mlp)
// blocks [1024,3072): adj -> fp8 BT streaming
__global__ __launch_bounds__(256) void k_prep(const float* __restrict__ adj,
                                              u8* __restrict__ BT8,
                                              const float* __restrict__ x,
                                              const float* __restrict__ h,
                                              const float* __restrict__ Wmlp,
                                              u8* __restrict__ A8) {
  __shared__ __align__(16) float Ws[DM * 68];
  uint32_t bi = blockIdx.x;
  if (bi >= 1024u) {
    const uint32_t lane = threadIdx.x & 63u;
    uint32_t gw = (bi - 1024u) * 4u + (threadIdx.x >> 6);
    for (uint32_t sc = gw; sc < 16384u; sc += 8192u) {
      const float4* src = reinterpret_cast<const float4*>(adj) + (size_t)sc * 512u + lane;
      float4 f[8];
#pragma unroll
      for (int q = 0; q < 8; ++q) f[q] = src[(size_t)q * 64];
      uint32_t row = sc >> 1;
      uint32_t s = row >> 12, w = row & 4095u;
      u8* dst = BT8 + (size_t)w * K_DIM + s * N_NODES + (sc & 1u) * 2048u + lane * 4u;
#pragma unroll
      for (int q = 0; q < 8; ++q) {
        int p = pk_fp8x4(f[q].x * 4096.f, f[q].y * 4096.f, f[q].z * 4096.f, f[q].w * 4096.f);
        *reinterpret_cast<int*>(dst + q * 256) = p;
      }
    }
    return;
  }
  uint32_t b2 = bi;                                   // 32 b x 2 s x 16 v0
  uint32_t v0 = (b2 & 15u) * 256u;
  uint32_t s  = (b2 >> 4) & 1u;
  uint32_t b  = b2 >> 5;
  for (uint32_t t = threadIdx.x; t < DM * 68; t += 256) {
    uint32_t d = t / 68u, c = t % 68u;
    Ws[t] = (c < 65u) ? Wmlp[d * 130u + s * 65u + c] : 0.f;
  }
  __syncthreads();

  const uint32_t tv = threadIdx.x & 63u;
  const uint32_t td = threadIdx.x >> 6;
  const uint32_t v  = v0 + tv * 4u;

  float acc[16][4];
#pragma unroll
  for (int d = 0; d < 16; ++d)
#pragma unroll
    for (int k = 0; k < 4; ++k) acc[d][k] = 0.f;

  for (int c0 = 0; c0 < 64; c0 += 4) {
    float4 in4[4];
#pragma unroll
    for (int j = 0; j < 4; ++j) {
      int c = c0 + j;
      const float* src = (c == 0) ? (x + (size_t)b * N_NODES + v)
                                  : (h + ((size_t)b * DM + (c - 1)) * N_NODES + v);
      in4[j] = *reinterpret_cast<const float4*>(src);
    }
#pragma unroll
    for (int d = 0; d < 16; ++d) {
      const float4 w4 = *reinterpret_cast<const float4*>(&Ws[(td * 16 + d) * 68 + c0]);
      acc[d][0] += w4.x * in4[0].x + w4.y * in4[1].x + w4.z * in4[2].x + w4.w * in4[3].x;
      acc[d][1] += w4.x * in4[0].y + w4.y * in4[1].y + w4.z * in4[2].y + w4.w * in4[3].y;
      acc[d][2] += w4.x * in4[0].z + w4.y * in4[1].z + w4.z * in4[2].z + w4.w * in4[3].z;
      acc[d][3] += w4.x * in4[0].w + w4.y * in4[1].w + w4.z * in4[2].w + w4.w * in4[3].w;
    }
  }
  {
    float4 in4 = *reinterpret_cast<const float4*>(h + ((size_t)b * DM + 63) * N_NODES + v);
#pragma unroll
    for (int d = 0; d < 16; ++d) {
      float w = Ws[(td * 16 + d) * 68 + 64];
      acc[d][0] += w * in4.x; acc[d][1] += w * in4.y;
      acc[d][2] += w * in4.z; acc[d][3] += w * in4.w;
    }
  }
#pragma unroll
  for (int d = 0; d < 16; ++d) {
    int p = pk_fp8x4(acc[d][0], acc[d][1], acc[d][2], acc[d][3]);
    *reinterpret_cast<int*>(A8 + (size_t)(b * DM + td * 16 + d) * K_DIM + s * N_NODES + v) = p;
  }
}

// ---------------- kernel 2 (FUSED): full-K GEMM + W_lin/PReLU/W_read epilogue.
// M-tile = 128 rows of M=(b*64+d) -> exactly 2 batches x all 64 d-channels, so
// the whole W_lin channel-mix is block-local. Split-K removed (K=8192 in-block).
// After the MFMA loop: two passes (b-half each): acc -> LDS gco tile (union over
// As/Bs), then f32 VALU epilogue writes out1/out0 directly. C0/C1 eliminated.
__global__ void k_gemm(const u8* __restrict__ A, const u8* __restrict__ BT,
                       const float* __restrict__ h,
                       const float* __restrict__ bmlp, const float* __restrict__ Wlin,
                       const float* __restrict__ blin, const float* __restrict__ Wread,
                       const float* __restrict__ bread, const float* __restrict__ pa,
                       float* __restrict__ out0, float* __restrict__ out1) {
  // union region: main loop As[4][128][32] + Bs[4][128][32] (32 KB) | gco[64][132] (33 KB)
  __shared__ __align__(32) char smem[64 * 132 * 4];
  __shared__ __align__(16) float sW[DM * 128];     // W_lin 32 KB (persistent)
  __shared__ __align__(16) float sbm[DM], sbl[DM], sWr[128];
  __shared__ __align__(16) float psum[8 * 128];

  u8 (*As)[128][32] = reinterpret_cast<u8(*)[128][32]>(smem);
  u8 (*Bs)[128][32] = reinterpret_cast<u8(*)[128][32]>(smem + 16384);
  float (*gco)[132] = reinterpret_cast<float(*)[132]>(smem);

  const int tid  = threadIdx.x;
  const int lane = tid & 63;
  const int wave = tid >> 6;
  const int wr = wave >> 1, wc = wave & 1;      // 2x2 wave grid, 64x64 each

  // bijective XCD swizzle (512 = 8*64): each XCD owns 2 y-panels x all 32 x
  uint32_t bi  = blockIdx.x;
  uint32_t bi2 = (bi & 7u) * 64u + (bi >> 3);
  const int xt = bi2 & 31, yt = bi2 >> 5;
  const int m0 = yt * 128, n0 = xt * 128;
  const int b0 = yt * 2;

  // weight/bias preload (region disjoint from As/Bs; first barrier orders it)
  for (int t = tid; t < DM * 128; t += 256) sW[t] = Wlin[t];
  if (tid < DM)  { sbm[tid] = bmlp[tid]; sbl[tid] = blin[tid]; }
  if (tid < 128) sWr[tid] = Wread[tid];
  const float aP = pa[0];
  const float br = bread[0];

  // staging addressing (verified layout): wave stages rows [wave*32, wave*32+32)
  const int srow  = lane >> 1;
  const int shalf = (lane & 1) * 16;
  const u8* Ag = A  + (size_t)(m0 + wave * 32 + srow) * K_DIM + shalf;
  const u8* Bg = BT + (size_t)(n0 + wave * 32 + srow) * K_DIM + shalf;
  u8* AsB[4]; u8* BsB[4];
#pragma unroll
  for (int q = 0; q < 4; ++q) { AsB[q] = &As[q][wave * 32][0]; BsB[q] = &Bs[q][wave * 32][0]; }

  floatx4 acc[4][4];
#pragma unroll
  for (int i = 0; i < 4; ++i)
#pragma unroll
    for (int j = 0; j < 4; ++j) acc[i][j] = (floatx4){0.f, 0.f, 0.f, 0.f};

  const int fm = lane & 15;
  const int fq = lane >> 4;
  const int SC1 = 0x7F7F7F7F;    // e8m0 scale = 1.0

  for (int k0 = 0; k0 < 8192; k0 += 128) {
#pragma unroll
    for (int q = 0; q < 4; ++q) GLOAD_LDS16(Ag + k0 + q * 32, AsB[q]);
#pragma unroll
    for (int q = 0; q < 4; ++q) GLOAD_LDS16(Bg + k0 + q * 32, BsB[q]);
    __syncthreads();

    i32x8 af[4], bfr[4];
#pragma unroll
    for (int i = 0; i < 4; ++i)
      af[i] = *reinterpret_cast<const i32x8*>(&As[fq][wr * 64 + i * 16 + fm][0]);
#pragma unroll
    for (int j = 0; j < 4; ++j)
      bfr[j] = *reinterpret_cast<const i32x8*>(&Bs[fq][wc * 64 + j * 16 + fm][0]);
#pragma unroll
    for (int i = 0; i < 4; ++i)
#pragma unroll
      for (int j = 0; j < 4; ++j)
        acc[i][j] = __builtin_amdgcn_mfma_scale_f32_16x16x128_f8f6f4(
            af[i], bfr[j], acc[i][j], 0, 0, 0, SC1, 0, SC1);
    __syncthreads();
  }

  // ---- fused epilogue, two passes (pass p handles b = b0+p, 64 gco rows) ----
  const float KS = 1.0f / 4096.0f;
  const int cr = (lane >> 4) * 4;
  const int cc = lane & 15;
  const int dsub = wave * 2 + (lane >> 5);      // 0..7: 8-channel group
  const int ncol = (lane & 31) * 4;             // 0..124: 4-n column group

  for (int p = 0; p < 2; ++p) {
    if (wr == p) {
      // gco[d][n] = acc/4096 + bmlp[d]   (d = i*16+cr+r, n = wc*64+j*16+cc)
#pragma unroll
      for (int i = 0; i < 4; ++i)
#pragma unroll
        for (int j = 0; j < 4; ++j) {
#pragma unroll
          for (int r = 0; r < 4; ++r) {
            int d = i * 16 + cr + r;
            gco[d][wc * 64 + j * 16 + cc] = acc[i][j][r] * KS + sbm[d];
          }
        }
    }
    __syncthreads();

    const int b = b0 + p;
    float z[8][4];
#pragma unroll
    for (int dd = 0; dd < 8; ++dd) {
      float bl = sbl[dsub * 8 + dd];
#pragma unroll
      for (int k = 0; k < 4; ++k) z[dd][k] = bl;
    }

    // W_lin first half: gco channels 0..63 from LDS
    for (int k0 = 0; k0 < 64; k0 += 4) {
      float4 g[4];
#pragma unroll
      for (int j = 0; j < 4; ++j)
        g[j] = *reinterpret_cast<const float4*>(&gco[k0 + j][ncol]);
#pragma unroll
      for (int dd = 0; dd < 8; ++dd) {
        const float4 w4 = *reinterpret_cast<const float4*>(&sW[(dsub * 8 + dd) * 128 + k0]);
        z[dd][0] += w4.x * g[0].x + w4.y * g[1].x + w4.z * g[2].x + w4.w * g[3].x;
        z[dd][1] += w4.x * g[0].y + w4.y * g[1].y + w4.z * g[2].y + w4.w * g[3].y;
        z[dd][2] += w4.x * g[0].z + w4.y * g[1].z + w4.z * g[2].z + w4.w * g[3].z;
        z[dd][3] += w4.x * g[0].w + w4.y * g[1].w + w4.z * g[2].w + w4.w * g[3].w;
      }
    }

    // W_lin second half: h channels; dsub==0 threads also copy h -> out1 and
    // accumulate the W_read h-part.
    const float* hb = h + (size_t)b * DM * N_NODES + n0 + ncol;
    float* o1b = out1 + (size_t)b * 128 * N_NODES + n0 + ncol;
    float hs[4] = {0.f, 0.f, 0.f, 0.f};
    for (int k0 = 0; k0 < 64; k0 += 4) {
      float4 hv[4];
#pragma unroll
      for (int j = 0; j < 4; ++j)
        hv[j] = *reinterpret_cast<const float4*>(hb + (size_t)(k0 + j) * N_NODES);
#pragma unroll
      for (int dd = 0; dd < 8; ++dd) {
        const float4 w4 = *reinterpret_cast<const float4*>(&sW[(dsub * 8 + dd) * 128 + 64 + k0]);
        z[dd][0] += w4.x * hv[0].x + w4.y * hv[1].x + w4.z * hv[2].x + w4.w * hv[3].x;
        z[dd][1] += w4.x * hv[0].y + w4.y * hv[1].y + w4.z * hv[2].y + w4.w * hv[3].y;
        z[dd][2] += w4.x * hv[0].z + w4.y * hv[1].z + w4.z * hv[2].z + w4.w * hv[3].z;
        z[dd][3] += w4.x * hv[0].w + w4.y * hv[1].w + w4.z * hv[2].w + w4.w * hv[3].w;
      }
      if (dsub == 0) {
#pragma unroll
        for (int j = 0; j < 4; ++j) {
          *reinterpret_cast<float4*>(o1b + (size_t)(64 + k0 + j) * N_NODES) = hv[j];
          float w = sWr[64 + k0 + j];
          hs[0] += w * hv[j].x; hs[1] += w * hv[j].y;
          hs[2] += w * hv[j].z; hs[3] += w * hv[j].w;
        }
      }
    }

    // PReLU + out1 z-channels + W_read partial
    float rp[4] = {0.f, 0.f, 0.f, 0.f};
#pragma unroll
    for (int dd = 0; dd < 8; ++dd) {
      int dp = dsub * 8 + dd;
      float4 o2;
      o2.x = z[dd][0] >= 0.f ? z[dd][0] : aP * z[dd][0];
      o2.y = z[dd][1] >= 0.f ? z[dd][1] : aP * z[dd][1];
      o2.z = z[dd][2] >= 0.f ? z[dd][2] : aP * z[dd][2];
      o2.w = z[dd][3] >= 0.f ? z[dd][3] : aP * z[dd][3];
      *reinterpret_cast<float4*>(o1b + (size_t)dp * N_NODES) = o2;
      float w = sWr[dp];
      rp[0] += w * o2.x; rp[1] += w * o2.y; rp[2] += w * o2.z; rp[3] += w * o2.w;
    }
    if (dsub == 0) {
      rp[0] += hs[0]; rp[1] += hs[1]; rp[2] += hs[2]; rp[3] += hs[3];
    }
    {
      float4 rv; rv.x = rp[0]; rv.y = rp[1]; rv.z = rp[2]; rv.w = rp[3];
      *reinterpret_cast<float4*>(&psum[dsub * 128 + ncol]) = rv;
    }
    __syncthreads();
    if (wave == 0 && lane < 32) {
      float s0[4];
#pragma unroll
      for (int k = 0; k < 4; ++k) {
        float s = br;
#pragma unroll
        for (int ds = 0; ds < 8; ++ds) s += psum[ds * 128 + ncol + k];
        s0[k] = s;
      }
      float4 ov; ov.x = s0[0]; ov.y = s0[1]; ov.z = s0[2]; ov.w = s0[3];
      *reinterpret_cast<float4*>(out0 + (size_t)b * N_NODES + n0 + ncol) = ov;
    }
    __syncthreads();   // gco/psum safe to overwrite in next pass
  }
}

extern "C" void kernel_launch(void* const* d_in, const int* in_sizes, int n_in,
                              void* d_out, int out_size, void* d_ws, size_t ws_size,
                              hipStream_t stream) {
  const float* x     = (const float*)d_in[0];
  const float* h     = (const float*)d_in[1];
  const float* adj   = (const float*)d_in[2];
  const float* Wmlp  = (const float*)d_in[3];
  const float* bmlp  = (const float*)d_in[4];
  const float* Wlin  = (const float*)d_in[5];
  const float* blin  = (const float*)d_in[6];
  const float* Wread = (const float*)d_in[7];
  const float* bread = (const float*)d_in[8];
  const float* pa    = (const float*)d_in[9];

  char* ws = (char*)d_ws;
  u8*    Abuf  = (u8*)ws;                        // 2048*8192 = 16 MiB
  u8*    BTbuf = (u8*)(ws + (16ull << 20));      // 4096*8192 = 32 MiB
  float* out0 = (float*)d_out;                   // [32,1,4096]
  float* out1 = out0 + 131072;                   // [32,128,4096]

  hipLaunchKernelGGL(k_prep, dim3(3072), dim3(256), 0, stream,
                     adj, BTbuf, x, h, Wmlp, Abuf);
  hipLaunchKernelGGL(k_gemm, dim3(512),  dim3(256), 0, stream,
                     Abuf, BTbuf, h, bmlp, Wlin, blin, Wread, bread, pa, out0, out1);
}